// Round 2
// baseline (301.346 us; speedup 1.0000x reference)
//
#include <hip/hip_runtime.h>
#include <hip/hip_bf16.h>
#include <math.h>

#define NN 8192
#define QSCALE (0.125f * 1.44269504088896f)   // fold 0.125 and log2(e) into Q

typedef __attribute__((ext_vector_type(8))) short short8;
typedef __attribute__((ext_vector_type(16))) float f32x16;

union U8 { unsigned u[4]; short8 v; };

__device__ inline unsigned short f2bf(float x) {
  union { float f; unsigned u; } t; t.f = x;
  unsigned r = t.u + 0x7fffu + ((t.u >> 16) & 1u);
  return (unsigned short)(r >> 16);
}
// packed bf16(lo) | bf16(hi)<<16 via HW instruction (RNE)
__device__ inline unsigned cvtpk(float lo, float hi) {
  unsigned r;
  asm("v_cvt_pk_bf16_f32 %0, %1, %2" : "=v"(r) : "v"(lo), "v"(hi));
  return r;
}

// ---------------------------------------------------------------------------
// Packed fragment layouts (all bf16, 1 MB each):
//  QP[c8][i][e] = Q[i][c8*8+e] * QSCALE   (c8 = 0..7, e = 0..7)
//  KP[c8][j][e] = K[j][c8*8+e]
//  VP[j8][d][e] = V[j8*8+e][d]            (j8 = 0..1023, d = 0..63)
//  HP[j8][d][e] = H[j8*8+e][d]
// A-frag (32x32x16, mfma m, half h): lane(l31,h) = P[row=l31][16m+8h+e]
//   -> chunk c8 = 2m+h, contiguous in l31  => coalesced dwordx4
// B-frag: lane(l31,h) = B[k=8h+e][col=l31] -> VP/HP chunk (jt>>3)+{h,2+h}
// ---------------------------------------------------------------------------
__global__ __launch_bounds__(256) void qkv_kernel(
    const float* __restrict__ X, const float* __restrict__ H,
    const float* __restrict__ Qw, const float* __restrict__ Qb,
    const float* __restrict__ Kw, const float* __restrict__ Kb,
    const float* __restrict__ Vw, const float* __restrict__ Vb,
    const float* __restrict__ bng, const float* __restrict__ bnb,
    const float* __restrict__ bnm, const float* __restrict__ bnv,
    unsigned short* __restrict__ QP, unsigned short* __restrict__ KP,
    unsigned short* __restrict__ VP, unsigned short* __restrict__ HP)
{
  int wid = (blockIdx.x * blockDim.x + threadIdx.x) >> 6; // 0..2047
  int d = threadIdx.x & 63;
  float4 w[16];

  // ---- Q phase (from X)
  for (int fq = 0; fq < 16; fq++) w[fq] = *(const float4*)(Qw + d*64 + fq*4);
  for (int rr = 0; rr < 4; rr++) {
    int r = wid*4 + rr;
    float a = Qb[d];
    for (int fq = 0; fq < 16; fq++) {
      float4 xv = *(const float4*)(X + r*64 + fq*4);
      a += w[fq].x*xv.x + w[fq].y*xv.y + w[fq].z*xv.z + w[fq].w*xv.w;
    }
    float s = a;
    for (int off = 32; off; off >>= 1) s += __shfl_xor(s, off);
    float mean = s * (1.f/64.f);
    float c = a - mean;
    float s2 = c*c;
    for (int off = 32; off; off >>= 1) s2 += __shfl_xor(s2, off);
    float q = c * rsqrtf(s2*(1.f/64.f) + 1e-5f);
    QP[(d>>3)*65536 + r*8 + (d&7)] = f2bf(q * QSCALE);
  }
  // ---- K phase (from H)
  for (int fq = 0; fq < 16; fq++) w[fq] = *(const float4*)(Kw + d*64 + fq*4);
  for (int rr = 0; rr < 4; rr++) {
    int r = wid*4 + rr;
    float a = Kb[d];
    for (int fq = 0; fq < 16; fq++) {
      float4 hv = *(const float4*)(H + r*64 + fq*4);
      a += w[fq].x*hv.x + w[fq].y*hv.y + w[fq].z*hv.z + w[fq].w*hv.w;
    }
    float s = a;
    for (int off = 32; off; off >>= 1) s += __shfl_xor(s, off);
    float mean = s * (1.f/64.f);
    float c = a - mean;
    float s2 = c*c;
    for (int off = 32; off; off >>= 1) s2 += __shfl_xor(s2, off);
    float k = c * rsqrtf(s2*(1.f/64.f) + 1e-5f);
    KP[(d>>3)*65536 + r*8 + (d&7)] = f2bf(k);
  }
  // ---- V phase (from H) + H transpose-pack
  for (int fq = 0; fq < 16; fq++) w[fq] = *(const float4*)(Vw + d*64 + fq*4);
  float bscale = rsqrtf(bnv[d] + 1e-5f) * bng[d];
  for (int rr = 0; rr < 4; rr++) {
    int r = wid*4 + rr;
    float a = Vb[d];
    for (int fq = 0; fq < 16; fq++) {
      float4 hv = *(const float4*)(H + r*64 + fq*4);
      a += w[fq].x*hv.x + w[fq].y*hv.y + w[fq].z*hv.z + w[fq].w*hv.w;
    }
    float v = (a - bnm[d]) * bscale + bnb[d];
    VP[(r>>3)*512 + d*8 + (r&7)] = f2bf(v);
    HP[(r>>3)*512 + d*8 + (r&7)] = f2bf(H[r*64 + d]);
  }
}

// ---------------------------------------------------------------------------
// pass 1: per-column partial sums of exp2(s'), s' = acc * M  (acc has
// 0.125*log2e folded in). No max needed: |s| <= 8 -> exp2 arg <= 11.6.
// Non-swapped: lane <-> column j -> M reads coalesced straight from global.
// ---------------------------------------------------------------------------
__global__ __launch_bounds__(256, 6) void pass1_kernel(
    const float* __restrict__ M, const unsigned short* __restrict__ QP,
    const unsigned short* __restrict__ KP, float* __restrict__ pd)
{
  int wj = (blockIdx.x * blockDim.x + threadIdx.x) >> 6;  // 0..8191
  int lane = threadIdx.x & 63;
  int l31 = lane & 31, h = lane >> 5;
  int jb = wj & 255, slice = wj >> 8;                     // 256 jb x 32 slices
  int j = jb*32 + l31;

  short8 kb[4];
  for (int m = 0; m < 4; m++)
    kb[m] = *(const short8*)(KP + (2*m + h)*65536 + j*8);

  float d0 = 0.f, d1 = 0.f, d2 = 0.f, d3 = 0.f;
  for (int t = 0; t < 8; t++) {
    int i0 = (slice*8 + t) * 32;
    f32x16 acc;
    for (int r = 0; r < 16; r++) acc[r] = 0.f;
    for (int m = 0; m < 4; m++) {
      short8 qa = *(const short8*)(QP + (2*m + h)*65536 + (i0 + l31)*8);
      acc = __builtin_amdgcn_mfma_f32_32x32x16_bf16(qa, kb[m], acc, 0, 0, 0);
    }
    float Mv[16];
    for (int r = 0; r < 16; r++) {
      int ir = (r&3) + 8*(r>>2) + 4*h;
      Mv[r] = M[(size_t)(i0 + ir)*NN + j];
    }
    d0 += exp2f(acc[0]*Mv[0]) + exp2f(acc[4]*Mv[4]) + exp2f(acc[8]*Mv[8])  + exp2f(acc[12]*Mv[12]);
    d1 += exp2f(acc[1]*Mv[1]) + exp2f(acc[5]*Mv[5]) + exp2f(acc[9]*Mv[9])  + exp2f(acc[13]*Mv[13]);
    d2 += exp2f(acc[2]*Mv[2]) + exp2f(acc[6]*Mv[6]) + exp2f(acc[10]*Mv[10]) + exp2f(acc[14]*Mv[14]);
    d3 += exp2f(acc[3]*Mv[3]) + exp2f(acc[7]*Mv[7]) + exp2f(acc[11]*Mv[11]) + exp2f(acc[15]*Mv[15]);
  }
  float drun = (d0 + d1) + (d2 + d3);
  drun += __shfl_xor(drun, 32);
  if (lane < 32) pd[(size_t)slice*NN + j] = drun;
}

// ---------------------------------------------------------------------------
// combine: cc[j] = log2(10 * D_j)   (p = exp2(s' - cc) = 0.1*exp(s)/D)
// ---------------------------------------------------------------------------
__global__ __launch_bounds__(256) void combine_kernel(
    const float* __restrict__ pd, float* __restrict__ colcc)
{
  int j = blockIdx.x * blockDim.x + threadIdx.x;
  float Dv = 0.f;
  for (int s = 0; s < 32; s++) Dv += pd[(size_t)s*NN + j];
  colcc[j] = log2f(Dv * 10.f);
}

// ---------------------------------------------------------------------------
// pass 2: out = A@V*alpha + M@H, fused.  Swapped GEMM (lane <-> i), M staged
// in XOR-swizzled f32 LDS tile (conflict-free b128 in both patterns), cc via
// LDS broadcast, P/M packed with v_cvt_pk_bf16_f32, half-swap via shfl_xor.
// WG = 256 thr (4 waves: iq = wid&1, dh = wid>>1), i-block 64 rows,
// j-slice 512 cols, 16 t-iters. Grid = 128 iblk x 16 slices.
// ---------------------------------------------------------------------------
__global__ __launch_bounds__(256, 6) void pass2_kernel(
    const float* __restrict__ M, const unsigned short* __restrict__ QP,
    const unsigned short* __restrict__ KP, const unsigned short* __restrict__ VP,
    const unsigned short* __restrict__ HP, const float* __restrict__ colcc,
    float* __restrict__ out)
{
  __shared__ __align__(16) float mt[2][64*32];
  __shared__ __align__(16) float cls[512];

  int iblk = blockIdx.x >> 4, slice = blockIdx.x & 15;
  int i0 = iblk * 64;
  int tid = threadIdx.x;
  int lane = tid & 63, wid = tid >> 6;
  int l31 = lane & 31, h = lane >> 5;
  int iq = wid & 1, dh = wid >> 1;
  int row = iq*32 + l31;            // LDS row for Mv reads
  int r7 = row & 7;

  // Q B-frags (fixed): lane(l31,h) -> Q[i0+iq*32+l31][16m+8h+e]*QSCALE
  short8 qb[4];
  for (int m = 0; m < 4; m++)
    qb[m] = *(const short8*)(QP + (2*m + h)*65536 + (i0 + row)*8);

  f32x16 oacc;
  for (int r = 0; r < 16; r++) oacc[r] = 0.f;

  // staging: thread -> (srow, 8-float group pair), XOR-swizzled 16B granules
  int srow = tid >> 2;
  int sg = tid & 3;
  const float* Msrc = M + (size_t)(i0 + srow)*NN + slice*512 + sg*8;
  int pg0 = ((2*sg)     ^ (srow & 7)) * 4 + srow*32;
  int pg1 = ((2*sg + 1) ^ (srow & 7)) * 4 + srow*32;

  {
    float4 ra = *(const float4*)(Msrc);
    float4 rb = *(const float4*)(Msrc + 4);
    *(float4*)(&mt[0][pg0]) = ra;
    *(float4*)(&mt[0][pg1]) = rb;
    cls[tid]       = colcc[slice*512 + tid];
    cls[tid + 256] = colcc[slice*512 + 256 + tid];
  }
  __syncthreads();

  for (int t = 0; t < 16; t++) {
    int jt = slice*512 + t*32;
    float4 ra, rb;
    if (t + 1 < 16) {
      ra = *(const float4*)(Msrc + (t+1)*32);
      rb = *(const float4*)(Msrc + (t+1)*32 + 4);
    }

    // s'^T = K x (Q*QSCALE)^T : D[col=i=l31][row=j=jr]
    f32x16 sacc;
    for (int r = 0; r < 16; r++) sacc[r] = 0.f;
    for (int m = 0; m < 4; m++) {
      short8 ka = *(const short8*)(KP + (2*m + h)*65536 + (jt + l31)*8);
      sacc = __builtin_amdgcn_mfma_f32_32x32x16_bf16(ka, qb[m], sacc, 0, 0, 0);
    }

    // V/H B-frags (coalesced packed chunks)
    int j8 = jt >> 3;
    const unsigned short* vbase = VP + (size_t)j8*512 + (dh*32 + l31)*8;
    const unsigned short* hbase = HP + (size_t)j8*512 + (dh*32 + l31)*8;
    short8 vb1 = *(const short8*)(vbase + h*512);
    short8 vb2 = *(const short8*)(vbase + (2 + h)*512);
    short8 hb1 = *(const short8*)(hbase + h*512);
    short8 hb2 = *(const short8*)(hbase + (2 + h)*512);

    const float* buf = mt[t & 1];

    // ---- half 1: q-groups 0,1 (j-local 0..15) ----
    unsigned pu[4], mu[4], ps[4], ms[4];
    for (int q = 0; q < 2; q++) {
      float4 mv = *(const float4*)(&buf[row*32 + (((2*q + h) ^ r7) << 2)]);
      float4 cc = *(const float4*)(&cls[t*32 + 8*q + 4*h]);
      float p0 = exp2f(sacc[4*q+0]*mv.x - cc.x);
      float p1 = exp2f(sacc[4*q+1]*mv.y - cc.y);
      float p2 = exp2f(sacc[4*q+2]*mv.z - cc.z);
      float p3 = exp2f(sacc[4*q+3]*mv.w - cc.w);
      pu[2*q]   = cvtpk(p0, p1);
      pu[2*q+1] = cvtpk(p2, p3);
      mu[2*q]   = cvtpk(mv.x, mv.y);
      mu[2*q+1] = cvtpk(mv.z, mv.w);
    }
    for (int k = 0; k < 4; k++) { ps[k] = __shfl_xor(pu[k], 32); ms[k] = __shfl_xor(mu[k], 32); }
    {
      U8 A1, Am1;
      A1.u[0]  = h ? ps[2] : pu[0];  A1.u[1]  = h ? ps[3] : pu[1];
      A1.u[2]  = h ? pu[2] : ps[0];  A1.u[3]  = h ? pu[3] : ps[1];
      Am1.u[0] = h ? ms[2] : mu[0];  Am1.u[1] = h ? ms[3] : mu[1];
      Am1.u[2] = h ? mu[2] : ms[0];  Am1.u[3] = h ? mu[3] : ms[1];
      oacc = __builtin_amdgcn_mfma_f32_32x32x16_bf16(A1.v,  vb1, oacc, 0, 0, 0);
      oacc = __builtin_amdgcn_mfma_f32_32x32x16_bf16(Am1.v, hb1, oacc, 0, 0, 0);
    }
    // ---- half 2: q-groups 2,3 (j-local 16..31) ----
    for (int q = 0; q < 2; q++) {
      int qq = q + 2;
      float4 mv = *(const float4*)(&buf[row*32 + (((2*qq + h) ^ r7) << 2)]);
      float4 cc = *(const float4*)(&cls[t*32 + 8*qq + 4*h]);
      float p0 = exp2f(sacc[4*qq+0]*mv.x - cc.x);
      float p1 = exp2f(sacc[4*qq+1]*mv.y - cc.y);
      float p2 = exp2f(sacc[4*qq+2]*mv.z - cc.z);
      float p3 = exp2f(sacc[4*qq+3]*mv.w - cc.w);
      pu[2*q]   = cvtpk(p0, p1);
      pu[2*q+1] = cvtpk(p2, p3);
      mu[2*q]   = cvtpk(mv.x, mv.y);
      mu[2*q+1] = cvtpk(mv.z, mv.w);
    }
    for (int k = 0; k < 4; k++) { ps[k] = __shfl_xor(pu[k], 32); ms[k] = __shfl_xor(mu[k], 32); }
    {
      U8 A2, Am2;
      A2.u[0]  = h ? ps[2] : pu[0];  A2.u[1]  = h ? ps[3] : pu[1];
      A2.u[2]  = h ? pu[2] : ps[0];  A2.u[3]  = h ? pu[3] : ps[1];
      Am2.u[0] = h ? ms[2] : mu[0];  Am2.u[1] = h ? ms[3] : mu[1];
      Am2.u[2] = h ? mu[2] : ms[0];  Am2.u[3] = h ? mu[3] : ms[1];
      oacc = __builtin_amdgcn_mfma_f32_32x32x16_bf16(A2.v,  vb2, oacc, 0, 0, 0);
      oacc = __builtin_amdgcn_mfma_f32_32x32x16_bf16(Am2.v, hb2, oacc, 0, 0, 0);
    }

    if (t + 1 < 16) {
      float* w = mt[(t+1) & 1];
      *(float4*)(&w[pg0]) = ra;
      *(float4*)(&w[pg1]) = rb;
    }
    __syncthreads();
  }

  for (int r = 0; r < 16; r++) {
    int orow = i0 + iq*32 + (r&3) + 8*(r>>2) + 4*h;
    int ocol = dh*32 + l31;
    atomicAdd(out + (size_t)orow*64 + ocol, oacc[r]);
  }
}

// ---------------------------------------------------------------------------
extern "C" void kernel_launch(void* const* d_in, const int* in_sizes, int n_in,
                              void* d_out, int out_size, void* d_ws, size_t ws_size,
                              hipStream_t stream) {
  const float* X   = (const float*)d_in[0];
  const float* H   = (const float*)d_in[1];
  const float* M   = (const float*)d_in[2];
  const float* Qw  = (const float*)d_in[3];
  const float* Qb  = (const float*)d_in[4];
  const float* Kw  = (const float*)d_in[5];
  const float* Kb  = (const float*)d_in[6];
  const float* Vw  = (const float*)d_in[7];
  const float* Vb  = (const float*)d_in[8];
  const float* bng = (const float*)d_in[9];
  const float* bnb = (const float*)d_in[10];
  const float* bnm = (const float*)d_in[11];
  const float* bnv = (const float*)d_in[12];
  float* out = (float*)d_out;

  char* ws = (char*)d_ws;
  const size_t MB = 1024*1024;
  unsigned short* QP = (unsigned short*)(ws);
  unsigned short* KP = (unsigned short*)(ws + 1*MB);
  unsigned short* VP = (unsigned short*)(ws + 2*MB);
  unsigned short* HP = (unsigned short*)(ws + 3*MB);
  float* pd    = (float*)(ws + 4*MB);
  float* colcc = (float*)(ws + 5*MB);

  hipMemsetAsync(d_out, 0, (size_t)out_size * sizeof(float), stream);

  qkv_kernel<<<512, 256, 0, stream>>>(X, H, Qw, Qb, Kw, Kb, Vw, Vb,
                                      bng, bnb, bnm, bnv, QP, KP, VP, HP);
  pass1_kernel<<<2048, 256, 0, stream>>>(M, QP, KP, pd);
  combine_kernel<<<32, 256, 0, stream>>>(pd, colcc);
  pass2_kernel<<<2048, 256, 0, stream>>>(M, QP, KP, VP, HP, colcc, out);
}

// Round 3
// 221.986 us; speedup vs baseline: 1.3575x; 1.3575x over previous
//
#include <hip/hip_runtime.h>
#include <hip/hip_bf16.h>
#include <math.h>

#define NN 8192
#define QSCALE (0.125f * 1.44269504088896f)   // fold 0.125 and log2(e) into Q

typedef __attribute__((ext_vector_type(8))) short short8;
typedef __attribute__((ext_vector_type(16))) float f32x16;
typedef __attribute__((ext_vector_type(4))) unsigned uint4e;
typedef __attribute__((ext_vector_type(2))) unsigned uint2e;

union W4 { uint4e u4; unsigned u[4]; short8 v; };

__device__ inline unsigned short f2bf(float x) {
  union { float f; unsigned u; } t; t.f = x;
  unsigned r = t.u + 0x7fffu + ((t.u >> 16) & 1u);
  return (unsigned short)(r >> 16);
}
__device__ inline unsigned cvtpk(float lo, float hi) {
  unsigned r;
  asm("v_cvt_pk_bf16_f32 %0, %1, %2" : "=v"(r) : "v"(lo), "v"(hi));
  return r;
}

// ---------------------------------------------------------------------------
// Kernel 1: Q/K/V/H pre-pack (unchanged from R2, plain launch bounds).
//  QP[c8][i][e] = Q[i][c8*8+e]*QSCALE ; KP same for K
//  VP[j8][d][e] = V[j8*8+e][d] ; HP same for H
// ---------------------------------------------------------------------------
__global__ __launch_bounds__(256) void qkv_kernel(
    const float* __restrict__ X, const float* __restrict__ H,
    const float* __restrict__ Qw, const float* __restrict__ Qb,
    const float* __restrict__ Kw, const float* __restrict__ Kb,
    const float* __restrict__ Vw, const float* __restrict__ Vb,
    const float* __restrict__ bng, const float* __restrict__ bnb,
    const float* __restrict__ bnm, const float* __restrict__ bnv,
    unsigned short* __restrict__ QP, unsigned short* __restrict__ KP,
    unsigned short* __restrict__ VP, unsigned short* __restrict__ HP)
{
  int wid = (blockIdx.x * blockDim.x + threadIdx.x) >> 6; // 0..2047
  int d = threadIdx.x & 63;
  float4 w[16];

  for (int fq = 0; fq < 16; fq++) w[fq] = *(const float4*)(Qw + d*64 + fq*4);
  for (int rr = 0; rr < 4; rr++) {
    int r = wid*4 + rr;
    float a = Qb[d];
    for (int fq = 0; fq < 16; fq++) {
      float4 xv = *(const float4*)(X + r*64 + fq*4);
      a += w[fq].x*xv.x + w[fq].y*xv.y + w[fq].z*xv.z + w[fq].w*xv.w;
    }
    float s = a;
    for (int off = 32; off; off >>= 1) s += __shfl_xor(s, off);
    float mean = s * (1.f/64.f);
    float c = a - mean;
    float s2 = c*c;
    for (int off = 32; off; off >>= 1) s2 += __shfl_xor(s2, off);
    float q = c * rsqrtf(s2*(1.f/64.f) + 1e-5f);
    QP[(d>>3)*65536 + r*8 + (d&7)] = f2bf(q * QSCALE);
  }
  for (int fq = 0; fq < 16; fq++) w[fq] = *(const float4*)(Kw + d*64 + fq*4);
  for (int rr = 0; rr < 4; rr++) {
    int r = wid*4 + rr;
    float a = Kb[d];
    for (int fq = 0; fq < 16; fq++) {
      float4 hv = *(const float4*)(H + r*64 + fq*4);
      a += w[fq].x*hv.x + w[fq].y*hv.y + w[fq].z*hv.z + w[fq].w*hv.w;
    }
    float s = a;
    for (int off = 32; off; off >>= 1) s += __shfl_xor(s, off);
    float mean = s * (1.f/64.f);
    float c = a - mean;
    float s2 = c*c;
    for (int off = 32; off; off >>= 1) s2 += __shfl_xor(s2, off);
    float k = c * rsqrtf(s2*(1.f/64.f) + 1e-5f);
    KP[(d>>3)*65536 + r*8 + (d&7)] = f2bf(k);
  }
  for (int fq = 0; fq < 16; fq++) w[fq] = *(const float4*)(Vw + d*64 + fq*4);
  float bscale = rsqrtf(bnv[d] + 1e-5f) * bng[d];
  for (int rr = 0; rr < 4; rr++) {
    int r = wid*4 + rr;
    float a = Vb[d];
    for (int fq = 0; fq < 16; fq++) {
      float4 hv = *(const float4*)(H + r*64 + fq*4);
      a += w[fq].x*hv.x + w[fq].y*hv.y + w[fq].z*hv.z + w[fq].w*hv.w;
    }
    float v = (a - bnm[d]) * bscale + bnb[d];
    VP[(r>>3)*512 + d*8 + (r&7)] = f2bf(v);
    HP[(r>>3)*512 + d*8 + (r&7)] = f2bf(H[r*64 + d]);
  }
}

// ---------------------------------------------------------------------------
// pass 1: per-column sums of exp2(s*M)  AND  M -> MT4 transpose-pack.
//  MT4 word index = jb4*32768 + i*4 + w  holds bf16 pair M[i][jb4*8+2w+(0,1)]
// Per-wave private LDS tile does the f32 transpose (32x32, stride 34,
// conflict-checked); writes are coalesced dwordx4.
// ---------------------------------------------------------------------------
__global__ __launch_bounds__(256) void pass1_kernel(
    const float* __restrict__ M, const unsigned short* __restrict__ QP,
    const unsigned short* __restrict__ KP, unsigned* __restrict__ MT4,
    float* __restrict__ pd)
{
  __shared__ __align__(16) float ld[4][32*34];
  int tid = threadIdx.x;
  int wj = (blockIdx.x * blockDim.x + tid) >> 6;  // 0..8191
  int lane = tid & 63;
  int wv = tid >> 6;
  int l31 = lane & 31, h = lane >> 5;
  int jb = wj & 255, slice = wj >> 8;             // 256 jb x 32 slices
  int j = jb*32 + l31;
  float* lds = ld[wv];

  short8 kb[4];
  for (int m = 0; m < 4; m++)
    kb[m] = *(const short8*)(KP + (2*m + h)*65536 + j*8);

  float d0 = 0.f, d1 = 0.f, d2 = 0.f, d3 = 0.f;
  for (int t = 0; t < 8; t++) {
    int i0 = (slice*8 + t) * 32;
    f32x16 acc;
    for (int r = 0; r < 16; r++) acc[r] = 0.f;
    for (int m = 0; m < 4; m++) {
      short8 qa = *(const short8*)(QP + (2*m + h)*65536 + (size_t)(i0 + l31)*8);
      acc = __builtin_amdgcn_mfma_f32_32x32x16_bf16(qa, kb[m], acc, 0, 0, 0);
    }
    float Mv[16];
#pragma unroll
    for (int r = 0; r < 16; r++) {
      int ir = (r&3) + 8*(r>>2) + 4*h;
      Mv[r] = M[(size_t)(i0 + ir)*NN + j];
      lds[ir*34 + l31] = Mv[r];
    }
    d0 += exp2f(acc[0]*Mv[0]) + exp2f(acc[4]*Mv[4]) + exp2f(acc[8]*Mv[8])   + exp2f(acc[12]*Mv[12]);
    d1 += exp2f(acc[1]*Mv[1]) + exp2f(acc[5]*Mv[5]) + exp2f(acc[9]*Mv[9])   + exp2f(acc[13]*Mv[13]);
    d2 += exp2f(acc[2]*Mv[2]) + exp2f(acc[6]*Mv[6]) + exp2f(acc[10]*Mv[10]) + exp2f(acc[14]*Mv[14]);
    d3 += exp2f(acc[3]*Mv[3]) + exp2f(acc[7]*Mv[7]) + exp2f(acc[11]*Mv[11]) + exp2f(acc[15]*Mv[15]);

    asm volatile("s_waitcnt lgkmcnt(0)" ::: "memory");  // wave-local transpose
    int ii = l31;
    int i_g = i0 + ii;
#pragma unroll
    for (int qq = 0; qq < 2; qq++) {
      int q = 2*h + qq;                     // h=0 -> q 0,1 ; h=1 -> q 2,3
      unsigned w0, w1, w2, w3;
      {
        float2 a2 = *(const float2*)(&lds[ii*34 + 8*q + 0]);
        float2 b2 = *(const float2*)(&lds[ii*34 + 8*q + 2]);
        float2 c2 = *(const float2*)(&lds[ii*34 + 8*q + 4]);
        float2 e2 = *(const float2*)(&lds[ii*34 + 8*q + 6]);
        w0 = cvtpk(a2.x, a2.y); w1 = cvtpk(b2.x, b2.y);
        w2 = cvtpk(c2.x, c2.y); w3 = cvtpk(e2.x, e2.y);
      }
      uint4e ww = {w0, w1, w2, w3};
      *(uint4e*)(MT4 + (size_t)(jb*4 + q)*32768 + (size_t)i_g*4) = ww;
    }
  }
  float drun = (d0 + d1) + (d2 + d3);
  drun += __shfl_xor(drun, 32);
  if (lane < 32) pd[(size_t)slice*NN + j] = drun;
}

// ---------------------------------------------------------------------------
// combine: cc[j] = log2(10 * D_j)
// ---------------------------------------------------------------------------
__global__ __launch_bounds__(256) void combine_kernel(
    const float* __restrict__ pd, float* __restrict__ colcc)
{
  int j = blockIdx.x * blockDim.x + threadIdx.x;
  float Dv = 0.f;
  for (int s = 0; s < 32; s++) Dv += pd[(size_t)s*NN + j];
  colcc[j] = log2f(Dv * 10.f);
}

// ---------------------------------------------------------------------------
// pass 2: out = alpha*A@V + M@H. Swapped sacc (lane=i). M arrives as MT4
// A-fragment words via coalesced global loads (no LDS in loop). P half-swap
// via v_permlane32_swap_b32 (VALU). cc via 2KB LDS broadcast table.
// WG = 256 (4 waves: iq = wid&1, dh = wid>>1); 64 i-rows x 512 j per WG.
// ---------------------------------------------------------------------------
__global__ __launch_bounds__(256) void pass2_kernel(
    const unsigned* __restrict__ MT4, const unsigned short* __restrict__ QP,
    const unsigned short* __restrict__ KP, const unsigned short* __restrict__ VP,
    const unsigned short* __restrict__ HP, const float* __restrict__ colcc,
    float* __restrict__ out)
{
  __shared__ __align__(16) float cls[512];

  int iblk = blockIdx.x >> 4, slice = blockIdx.x & 15;
  int i0 = iblk * 64;
  int tid = threadIdx.x;
  int lane = tid & 63, wid = tid >> 6;
  int l31 = lane & 31, h = lane >> 5;
  int iq = wid & 1, dh = wid >> 1;
  int row = iq*32 + l31;
  int i_g = i0 + row;

  short8 qb[4];
  for (int m = 0; m < 4; m++)
    qb[m] = *(const short8*)(QP + (2*m + h)*65536 + (size_t)i_g*8);

  cls[tid]       = colcc[slice*512 + tid];
  cls[tid + 256] = colcc[slice*512 + 256 + tid];
  __syncthreads();

  f32x16 oacc;
  for (int r = 0; r < 16; r++) oacc[r] = 0.f;

  const unsigned* mbase = MT4 + (size_t)i_g*4;

  for (int t = 0; t < 16; t++) {
    int jt = slice*512 + t*32;
    int jtb = jt >> 3;

    // ---- M fragment loads (coalesced; MT4 is L3-resident) ----
    W4 A0, A1; uint2e E0, E1;
    A0.u4 = *(const uint4e*)(mbase + (size_t)(jtb + h)*32768);
    A1.u4 = *(const uint4e*)(mbase + (size_t)(jtb + 2 + h)*32768);
    E0    = *(const uint2e*)(mbase + (size_t)(jtb + (h ? 0 : 1))*32768 + 2*h);
    E1    = *(const uint2e*)(mbase + (size_t)(jtb + (h ? 2 : 3))*32768 + 2*h);

    // ---- s'^T = K x (Q*QSCALE)^T : lane l31 = i, regs = j ----
    f32x16 sacc;
    for (int r = 0; r < 16; r++) sacc[r] = 0.f;
    for (int m = 0; m < 4; m++) {
      short8 ka = *(const short8*)(KP + (2*m + h)*65536 + (size_t)(jt + l31)*8);
      sacc = __builtin_amdgcn_mfma_f32_32x32x16_bf16(ka, qb[m], sacc, 0, 0, 0);
    }

    // ---- select M words for this lane's jr set ----
    unsigned mw[8];
    mw[0] = h ? E0.x    : A0.u[0];  mw[1] = h ? E0.y    : A0.u[1];
    mw[2] = h ? A0.u[2] : E0.x;     mw[3] = h ? A0.u[3] : E0.y;
    mw[4] = h ? E1.x    : A1.u[0];  mw[5] = h ? E1.y    : A1.u[1];
    mw[6] = h ? A1.u[2] : E1.x;     mw[7] = h ? A1.u[3] : E1.y;

    // ---- p = exp2(s*M - cc) ----
    float p[16];
#pragma unroll
    for (int q = 0; q < 4; q++) {
      float4 cc = *(const float4*)(&cls[t*32 + 8*q + 4*h]);
      unsigned wa = mw[2*q], wb = mw[2*q + 1];
      float m0 = __uint_as_float(wa << 16);
      float m1 = __uint_as_float(wa & 0xffff0000u);
      float m2 = __uint_as_float(wb << 16);
      float m3 = __uint_as_float(wb & 0xffff0000u);
      p[4*q+0] = exp2f(fmaf(sacc[4*q+0], m0, -cc.x));
      p[4*q+1] = exp2f(fmaf(sacc[4*q+1], m1, -cc.y));
      p[4*q+2] = exp2f(fmaf(sacc[4*q+2], m2, -cc.z));
      p[4*q+3] = exp2f(fmaf(sacc[4*q+3], m3, -cc.w));
    }
    unsigned pu[8];
#pragma unroll
    for (int k = 0; k < 8; k++) pu[k] = cvtpk(p[2*k], p[2*k+1]);

    // half-swaps: (pu0,pu2) (pu1,pu3) (pu4,pu6) (pu5,pu7) -> A-frag words
    asm volatile("v_permlane32_swap_b32 %0, %1" : "+v"(pu[0]), "+v"(pu[2]));
    asm volatile("v_permlane32_swap_b32 %0, %1" : "+v"(pu[1]), "+v"(pu[3]));
    asm volatile("v_permlane32_swap_b32 %0, %1" : "+v"(pu[4]), "+v"(pu[6]));
    asm volatile("v_permlane32_swap_b32 %0, %1" : "+v"(pu[5]), "+v"(pu[7]));

    W4 PA0, PA1;
    PA0.u[0] = pu[0]; PA0.u[1] = pu[1]; PA0.u[2] = pu[2]; PA0.u[3] = pu[3];
    PA1.u[0] = pu[4]; PA1.u[1] = pu[5]; PA1.u[2] = pu[6]; PA1.u[3] = pu[7];

    // ---- V/H B-frags ----
    int j8 = jt >> 3;
    const unsigned short* vbase = VP + (size_t)j8*512 + (dh*32 + l31)*8;
    const unsigned short* hbase = HP + (size_t)j8*512 + (dh*32 + l31)*8;
    short8 vb1 = *(const short8*)(vbase + h*512);
    short8 vb2 = *(const short8*)(vbase + (2 + h)*512);
    short8 hb1 = *(const short8*)(hbase + h*512);
    short8 hb2 = *(const short8*)(hbase + (2 + h)*512);

    oacc = __builtin_amdgcn_mfma_f32_32x32x16_bf16(PA0.v, vb1, oacc, 0, 0, 0);
    oacc = __builtin_amdgcn_mfma_f32_32x32x16_bf16(PA1.v, vb2, oacc, 0, 0, 0);
    oacc = __builtin_amdgcn_mfma_f32_32x32x16_bf16(A0.v,  hb1, oacc, 0, 0, 0);
    oacc = __builtin_amdgcn_mfma_f32_32x32x16_bf16(A1.v,  hb2, oacc, 0, 0, 0);
  }

  for (int r = 0; r < 16; r++) {
    int orow = i0 + iq*32 + (r&3) + 8*(r>>2) + 4*h;
    int ocol = dh*32 + l31;
    atomicAdd(out + (size_t)orow*64 + ocol, oacc[r]);
  }
}

// ---------------------------------------------------------------------------
extern "C" void kernel_launch(void* const* d_in, const int* in_sizes, int n_in,
                              void* d_out, int out_size, void* d_ws, size_t ws_size,
                              hipStream_t stream) {
  const float* X   = (const float*)d_in[0];
  const float* H   = (const float*)d_in[1];
  const float* M   = (const float*)d_in[2];
  const float* Qw  = (const float*)d_in[3];
  const float* Qb  = (const float*)d_in[4];
  const float* Kw  = (const float*)d_in[5];
  const float* Kb  = (const float*)d_in[6];
  const float* Vw  = (const float*)d_in[7];
  const float* Vb  = (const float*)d_in[8];
  const float* bng = (const float*)d_in[9];
  const float* bnb = (const float*)d_in[10];
  const float* bnm = (const float*)d_in[11];
  const float* bnv = (const float*)d_in[12];
  float* out = (float*)d_out;

  char* ws = (char*)d_ws;
  const size_t MB = 1024*1024;
  unsigned* MT4       = (unsigned*)(ws);                 // 128 MB
  unsigned short* QP  = (unsigned short*)(ws + 128*MB);  // 1 MB
  unsigned short* KP  = (unsigned short*)(ws + 129*MB);
  unsigned short* VP  = (unsigned short*)(ws + 130*MB);
  unsigned short* HP  = (unsigned short*)(ws + 131*MB);
  float* pd           = (float*)(ws + 132*MB);           // 1 MB
  float* colcc        = (float*)(ws + 133*MB);           // 32 KB

  hipMemsetAsync(d_out, 0, (size_t)out_size * sizeof(float), stream);

  qkv_kernel<<<512, 256, 0, stream>>>(X, H, Qw, Qb, Kw, Kb, Vw, Vb,
                                      bng, bnb, bnm, bnv, QP, KP, VP, HP);
  pass1_kernel<<<2048, 256, 0, stream>>>(M, QP, KP, MT4, pd);
  combine_kernel<<<32, 256, 0, stream>>>(pd, colcc);
  pass2_kernel<<<2048, 256, 0, stream>>>(MT4, QP, KP, VP, HP, colcc, out);
}

// Round 4
// 200.707 us; speedup vs baseline: 1.5014x; 1.1060x over previous
//
#include <hip/hip_runtime.h>
#include <hip/hip_bf16.h>
#include <math.h>

#define NN 8192
#define QSCALE (0.125f * 1.44269504088896f)   // fold 0.125 and log2(e) into Q
#define OSZ (8192*64)

typedef __attribute__((ext_vector_type(8))) short short8;
typedef __attribute__((ext_vector_type(16))) float f32x16;
typedef __attribute__((ext_vector_type(4))) unsigned uint4e;
typedef __attribute__((ext_vector_type(2))) unsigned uint2e;

union W4 { uint4e u4; unsigned u[4]; short8 v; };

__device__ inline unsigned short f2bf(float x) {
  union { float f; unsigned u; } t; t.f = x;
  unsigned r = t.u + 0x7fffu + ((t.u >> 16) & 1u);
  return (unsigned short)(r >> 16);
}
__device__ inline unsigned cvtpk(float lo, float hi) {
  unsigned r;
  asm("v_cvt_pk_bf16_f32 %0, %1, %2" : "=v"(r) : "v"(lo), "v"(hi));
  return r;
}

// ---------------------------------------------------------------------------
// Kernel 1: Q/K/V/H pre-pack.
//  QP[c8][i][e] = Q[i][c8*8+e]*QSCALE ; KP same for K
//  VP[j8][d][e] = V[j8*8+e][d] ; HP same for H
// ---------------------------------------------------------------------------
__global__ __launch_bounds__(256) void qkv_kernel(
    const float* __restrict__ X, const float* __restrict__ H,
    const float* __restrict__ Qw, const float* __restrict__ Qb,
    const float* __restrict__ Kw, const float* __restrict__ Kb,
    const float* __restrict__ Vw, const float* __restrict__ Vb,
    const float* __restrict__ bng, const float* __restrict__ bnb,
    const float* __restrict__ bnm, const float* __restrict__ bnv,
    unsigned short* __restrict__ QP, unsigned short* __restrict__ KP,
    unsigned short* __restrict__ VP, unsigned short* __restrict__ HP)
{
  int wid = (blockIdx.x * blockDim.x + threadIdx.x) >> 6; // 0..2047
  int d = threadIdx.x & 63;
  float4 w[16];

  for (int fq = 0; fq < 16; fq++) w[fq] = *(const float4*)(Qw + d*64 + fq*4);
  for (int rr = 0; rr < 4; rr++) {
    int r = wid*4 + rr;
    float a = Qb[d];
    for (int fq = 0; fq < 16; fq++) {
      float4 xv = *(const float4*)(X + r*64 + fq*4);
      a += w[fq].x*xv.x + w[fq].y*xv.y + w[fq].z*xv.z + w[fq].w*xv.w;
    }
    float s = a;
    for (int off = 32; off; off >>= 1) s += __shfl_xor(s, off);
    float mean = s * (1.f/64.f);
    float c = a - mean;
    float s2 = c*c;
    for (int off = 32; off; off >>= 1) s2 += __shfl_xor(s2, off);
    float q = c * rsqrtf(s2*(1.f/64.f) + 1e-5f);
    QP[(d>>3)*65536 + r*8 + (d&7)] = f2bf(q * QSCALE);
  }
  for (int fq = 0; fq < 16; fq++) w[fq] = *(const float4*)(Kw + d*64 + fq*4);
  for (int rr = 0; rr < 4; rr++) {
    int r = wid*4 + rr;
    float a = Kb[d];
    for (int fq = 0; fq < 16; fq++) {
      float4 hv = *(const float4*)(H + r*64 + fq*4);
      a += w[fq].x*hv.x + w[fq].y*hv.y + w[fq].z*hv.z + w[fq].w*hv.w;
    }
    float s = a;
    for (int off = 32; off; off >>= 1) s += __shfl_xor(s, off);
    float mean = s * (1.f/64.f);
    float c = a - mean;
    float s2 = c*c;
    for (int off = 32; off; off >>= 1) s2 += __shfl_xor(s2, off);
    float k = c * rsqrtf(s2*(1.f/64.f) + 1e-5f);
    KP[(d>>3)*65536 + r*8 + (d&7)] = f2bf(k);
  }
  for (int fq = 0; fq < 16; fq++) w[fq] = *(const float4*)(Vw + d*64 + fq*4);
  float bscale = rsqrtf(bnv[d] + 1e-5f) * bng[d];
  for (int rr = 0; rr < 4; rr++) {
    int r = wid*4 + rr;
    float a = Vb[d];
    for (int fq = 0; fq < 16; fq++) {
      float4 hv = *(const float4*)(H + r*64 + fq*4);
      a += w[fq].x*hv.x + w[fq].y*hv.y + w[fq].z*hv.z + w[fq].w*hv.w;
    }
    float v = (a - bnm[d]) * bscale + bnb[d];
    VP[(r>>3)*512 + d*8 + (r&7)] = f2bf(v);
    HP[(r>>3)*512 + d*8 + (r&7)] = f2bf(H[r*64 + d]);
  }
}

// ---------------------------------------------------------------------------
// pass 1: per-column sums of exp2(s*M)  AND  M -> MT4 transpose-pack (bf16).
// M loads are nontemporal (single-use stream; keep L3 for MT4).
// ---------------------------------------------------------------------------
__global__ __launch_bounds__(256) void pass1_kernel(
    const float* __restrict__ M, const unsigned short* __restrict__ QP,
    const unsigned short* __restrict__ KP, unsigned* __restrict__ MT4,
    float* __restrict__ pd)
{
  __shared__ __align__(16) float ld[4][32*34];
  int tid = threadIdx.x;
  int wj = (blockIdx.x * blockDim.x + tid) >> 6;  // 0..8191
  int lane = tid & 63;
  int wv = tid >> 6;
  int l31 = lane & 31, h = lane >> 5;
  int jb = wj & 255, slice = wj >> 8;             // 256 jb x 32 slices
  int j = jb*32 + l31;
  float* lds = ld[wv];

  short8 kb[4];
  for (int m = 0; m < 4; m++)
    kb[m] = *(const short8*)(KP + (2*m + h)*65536 + j*8);

  float d0 = 0.f, d1 = 0.f, d2 = 0.f, d3 = 0.f;
  for (int t = 0; t < 8; t++) {
    int i0 = (slice*8 + t) * 32;
    f32x16 acc;
    for (int r = 0; r < 16; r++) acc[r] = 0.f;
    for (int m = 0; m < 4; m++) {
      short8 qa = *(const short8*)(QP + (2*m + h)*65536 + (size_t)(i0 + l31)*8);
      acc = __builtin_amdgcn_mfma_f32_32x32x16_bf16(qa, kb[m], acc, 0, 0, 0);
    }
    float Mv[16];
#pragma unroll
    for (int r = 0; r < 16; r++) {
      int ir = (r&3) + 8*(r>>2) + 4*h;
      Mv[r] = __builtin_nontemporal_load(M + (size_t)(i0 + ir)*NN + j);
      lds[ir*34 + l31] = Mv[r];
    }
    d0 += exp2f(acc[0]*Mv[0]) + exp2f(acc[4]*Mv[4]) + exp2f(acc[8]*Mv[8])   + exp2f(acc[12]*Mv[12]);
    d1 += exp2f(acc[1]*Mv[1]) + exp2f(acc[5]*Mv[5]) + exp2f(acc[9]*Mv[9])   + exp2f(acc[13]*Mv[13]);
    d2 += exp2f(acc[2]*Mv[2]) + exp2f(acc[6]*Mv[6]) + exp2f(acc[10]*Mv[10]) + exp2f(acc[14]*Mv[14]);
    d3 += exp2f(acc[3]*Mv[3]) + exp2f(acc[7]*Mv[7]) + exp2f(acc[11]*Mv[11]) + exp2f(acc[15]*Mv[15]);

    asm volatile("s_waitcnt lgkmcnt(0)" ::: "memory");  // wave-local transpose
    int ii = l31;
    int i_g = i0 + ii;
#pragma unroll
    for (int qq = 0; qq < 2; qq++) {
      int q = 2*h + qq;                     // h=0 -> q 0,1 ; h=1 -> q 2,3
      unsigned w0, w1, w2, w3;
      {
        float2 a2 = *(const float2*)(&lds[ii*34 + 8*q + 0]);
        float2 b2 = *(const float2*)(&lds[ii*34 + 8*q + 2]);
        float2 c2 = *(const float2*)(&lds[ii*34 + 8*q + 4]);
        float2 e2 = *(const float2*)(&lds[ii*34 + 8*q + 6]);
        w0 = cvtpk(a2.x, a2.y); w1 = cvtpk(b2.x, b2.y);
        w2 = cvtpk(c2.x, c2.y); w3 = cvtpk(e2.x, e2.y);
      }
      uint4e ww = {w0, w1, w2, w3};
      *(uint4e*)(MT4 + (size_t)(jb*4 + q)*32768 + (size_t)i_g*4) = ww;
    }
  }
  float drun = (d0 + d1) + (d2 + d3);
  drun += __shfl_xor(drun, 32);
  if (lane < 32) pd[(size_t)slice*NN + j] = drun;
}

// ---------------------------------------------------------------------------
// combine: cc[j] = log2(10 * D_j)
// ---------------------------------------------------------------------------
__global__ __launch_bounds__(256) void combine_kernel(
    const float* __restrict__ pd, float* __restrict__ colcc)
{
  int j = blockIdx.x * blockDim.x + threadIdx.x;
  float Dv = 0.f;
  for (int s = 0; s < 32; s++) Dv += pd[(size_t)s*NN + j];
  colcc[j] = log2f(Dv * 10.f);
}

// ---------------------------------------------------------------------------
// pass 2: partial out = alpha*A@V + M@H for one j-slice. No atomics: each
// WG stores its 16 regs to opart[slice]; reduce_kernel sums slices.
// ---------------------------------------------------------------------------
__global__ __launch_bounds__(256) void pass2_kernel(
    const unsigned* __restrict__ MT4, const unsigned short* __restrict__ QP,
    const unsigned short* __restrict__ KP, const unsigned short* __restrict__ VP,
    const unsigned short* __restrict__ HP, const float* __restrict__ colcc,
    float* __restrict__ opart)
{
  __shared__ __align__(16) float cls[512];

  int iblk = blockIdx.x >> 4, slice = blockIdx.x & 15;
  int i0 = iblk * 64;
  int tid = threadIdx.x;
  int lane = tid & 63, wid = tid >> 6;
  int l31 = lane & 31, h = lane >> 5;
  int iq = wid & 1, dh = wid >> 1;
  int row = iq*32 + l31;
  int i_g = i0 + row;

  short8 qb[4];
  for (int m = 0; m < 4; m++)
    qb[m] = *(const short8*)(QP + (2*m + h)*65536 + (size_t)i_g*8);

  cls[tid]       = colcc[slice*512 + tid];
  cls[tid + 256] = colcc[slice*512 + 256 + tid];
  __syncthreads();

  f32x16 oacc;
  for (int r = 0; r < 16; r++) oacc[r] = 0.f;

  const unsigned* mbase = MT4 + (size_t)i_g*4;

  for (int t = 0; t < 16; t++) {
    int jt = slice*512 + t*32;
    int jtb = jt >> 3;

    // ---- M fragment loads (coalesced; MT4 should be L3-resident) ----
    W4 A0, A1; uint2e E0, E1;
    A0.u4 = *(const uint4e*)(mbase + (size_t)(jtb + h)*32768);
    A1.u4 = *(const uint4e*)(mbase + (size_t)(jtb + 2 + h)*32768);
    E0    = *(const uint2e*)(mbase + (size_t)(jtb + (h ? 0 : 1))*32768 + 2*h);
    E1    = *(const uint2e*)(mbase + (size_t)(jtb + (h ? 2 : 3))*32768 + 2*h);

    // ---- s'^T = K x (Q*QSCALE)^T : lane l31 = i, regs = j ----
    f32x16 sacc;
    for (int r = 0; r < 16; r++) sacc[r] = 0.f;
    for (int m = 0; m < 4; m++) {
      short8 ka = *(const short8*)(KP + (2*m + h)*65536 + (size_t)(jt + l31)*8);
      sacc = __builtin_amdgcn_mfma_f32_32x32x16_bf16(ka, qb[m], sacc, 0, 0, 0);
    }

    // ---- select M words for this lane's jr set ----
    unsigned mw[8];
    mw[0] = h ? E0.x    : A0.u[0];  mw[1] = h ? E0.y    : A0.u[1];
    mw[2] = h ? A0.u[2] : E0.x;     mw[3] = h ? A0.u[3] : E0.y;
    mw[4] = h ? E1.x    : A1.u[0];  mw[5] = h ? E1.y    : A1.u[1];
    mw[6] = h ? A1.u[2] : E1.x;     mw[7] = h ? A1.u[3] : E1.y;

    // ---- p = exp2(s*M - cc) ----
    float p[16];
#pragma unroll
    for (int q = 0; q < 4; q++) {
      float4 cc = *(const float4*)(&cls[t*32 + 8*q + 4*h]);
      unsigned wa = mw[2*q], wb = mw[2*q + 1];
      float m0 = __uint_as_float(wa << 16);
      float m1 = __uint_as_float(wa & 0xffff0000u);
      float m2 = __uint_as_float(wb << 16);
      float m3 = __uint_as_float(wb & 0xffff0000u);
      p[4*q+0] = exp2f(fmaf(sacc[4*q+0], m0, -cc.x));
      p[4*q+1] = exp2f(fmaf(sacc[4*q+1], m1, -cc.y));
      p[4*q+2] = exp2f(fmaf(sacc[4*q+2], m2, -cc.z));
      p[4*q+3] = exp2f(fmaf(sacc[4*q+3], m3, -cc.w));
    }
    unsigned pu[8];
#pragma unroll
    for (int k = 0; k < 8; k++) pu[k] = cvtpk(p[2*k], p[2*k+1]);

    asm volatile("v_permlane32_swap_b32 %0, %1" : "+v"(pu[0]), "+v"(pu[2]));
    asm volatile("v_permlane32_swap_b32 %0, %1" : "+v"(pu[1]), "+v"(pu[3]));
    asm volatile("v_permlane32_swap_b32 %0, %1" : "+v"(pu[4]), "+v"(pu[6]));
    asm volatile("v_permlane32_swap_b32 %0, %1" : "+v"(pu[5]), "+v"(pu[7]));

    W4 PA0, PA1;
    PA0.u[0] = pu[0]; PA0.u[1] = pu[1]; PA0.u[2] = pu[2]; PA0.u[3] = pu[3];
    PA1.u[0] = pu[4]; PA1.u[1] = pu[5]; PA1.u[2] = pu[6]; PA1.u[3] = pu[7];

    // ---- V/H B-frags ----
    int j8 = jt >> 3;
    const unsigned short* vbase = VP + (size_t)j8*512 + (dh*32 + l31)*8;
    const unsigned short* hbase = HP + (size_t)j8*512 + (dh*32 + l31)*8;
    short8 vb1 = *(const short8*)(vbase + h*512);
    short8 vb2 = *(const short8*)(vbase + (2 + h)*512);
    short8 hb1 = *(const short8*)(hbase + h*512);
    short8 hb2 = *(const short8*)(hbase + (2 + h)*512);

    oacc = __builtin_amdgcn_mfma_f32_32x32x16_bf16(PA0.v, vb1, oacc, 0, 0, 0);
    oacc = __builtin_amdgcn_mfma_f32_32x32x16_bf16(PA1.v, vb2, oacc, 0, 0, 0);
    oacc = __builtin_amdgcn_mfma_f32_32x32x16_bf16(A0.v,  hb1, oacc, 0, 0, 0);
    oacc = __builtin_amdgcn_mfma_f32_32x32x16_bf16(A1.v,  hb2, oacc, 0, 0, 0);
  }

  float* obase = opart + (size_t)slice*OSZ;
#pragma unroll
  for (int r = 0; r < 16; r++) {
    int orow = i0 + iq*32 + (r&3) + 8*(r>>2) + 4*h;
    int ocol = dh*32 + l31;
    obase[(size_t)orow*64 + ocol] = oacc[r];
  }
}

// ---------------------------------------------------------------------------
// reduce: out = sum over 16 slices of opart  (float4, fully coalesced)
// ---------------------------------------------------------------------------
__global__ __launch_bounds__(256) void reduce_kernel(
    const float* __restrict__ opart, float* __restrict__ out)
{
  int e4 = blockIdx.x * blockDim.x + threadIdx.x;   // 0..131071
  const float4* p = (const float4*)opart;
  float4 a = p[e4];
#pragma unroll
  for (int s = 1; s < 16; s++) {
    float4 b = p[(size_t)s*(OSZ/4) + e4];
    a.x += b.x; a.y += b.y; a.z += b.z; a.w += b.w;
  }
  ((float4*)out)[e4] = a;
}

// ---------------------------------------------------------------------------
extern "C" void kernel_launch(void* const* d_in, const int* in_sizes, int n_in,
                              void* d_out, int out_size, void* d_ws, size_t ws_size,
                              hipStream_t stream) {
  const float* X   = (const float*)d_in[0];
  const float* H   = (const float*)d_in[1];
  const float* M   = (const float*)d_in[2];
  const float* Qw  = (const float*)d_in[3];
  const float* Qb  = (const float*)d_in[4];
  const float* Kw  = (const float*)d_in[5];
  const float* Kb  = (const float*)d_in[6];
  const float* Vw  = (const float*)d_in[7];
  const float* Vb  = (const float*)d_in[8];
  const float* bng = (const float*)d_in[9];
  const float* bnb = (const float*)d_in[10];
  const float* bnm = (const float*)d_in[11];
  const float* bnv = (const float*)d_in[12];
  float* out = (float*)d_out;

  char* ws = (char*)d_ws;
  const size_t MB = 1024*1024;
  unsigned* MT4       = (unsigned*)(ws);                 // 128 MB
  unsigned short* QP  = (unsigned short*)(ws + 128*MB);  // 1 MB
  unsigned short* KP  = (unsigned short*)(ws + 129*MB);
  unsigned short* VP  = (unsigned short*)(ws + 130*MB);
  unsigned short* HP  = (unsigned short*)(ws + 131*MB);
  float* pd           = (float*)(ws + 132*MB);           // 1 MB
  float* colcc        = (float*)(ws + 133*MB);           // 32 KB
  float* opart        = (float*)(ws + 134*MB);           // 32 MB

  qkv_kernel<<<512, 256, 0, stream>>>(X, H, Qw, Qb, Kw, Kb, Vw, Vb,
                                      bng, bnb, bnm, bnv, QP, KP, VP, HP);
  pass1_kernel<<<2048, 256, 0, stream>>>(M, QP, KP, MT4, pd);
  combine_kernel<<<32, 256, 0, stream>>>(pd, colcc);
  pass2_kernel<<<2048, 256, 0, stream>>>(MT4, QP, KP, VP, HP, colcc, opart);
  reduce_kernel<<<512, 256, 0, stream>>>(opart, out);
}